// Round 5
// baseline (260.030 us; speedup 1.0000x reference)
//
#include <hip/hip_runtime.h>
#include <math.h>

#define B_   64
#define NPB  3468            // points (visual words) per batch
#define NPTS (B_ * NPB)      // 221952
#define KC   248
#define D_   64
#define NV   (KC * D_)       // 15872 per-batch vlad elements
#define OCT  8               // norms: chunks per batch
#define N4PB (NPB * D_ / 4)  // 55488 float4s per batch
#define N4CH (N4PB / OCT)    // 6936 float4s per chunk
#define CHPB 55              // aggregation chunks per batch (54*64 + 12)
#define APAD 65
#define SLIM 64              // sorted code rows staged in LDS

// ---------------- pass 1a: partial sums of squares per (b, chunk, d)
__global__ __launch_bounds__(256) void norms_part_kernel(const float* __restrict__ feat,
                                                         float* __restrict__ partial) {
    int b = blockIdx.x >> 3, o = blockIdx.x & 7, t = threadIdx.x;
    const float4* f = (const float4*)(feat + (size_t)b * (NPB * D_));
    float ax = 0.f, ay = 0.f, az = 0.f, aw = 0.f;
    for (int j = 0; j < (N4CH + 255) / 256; ++j) {
        int loc = t + j * 256;
        if (loc < N4CH) {
            float4 a = f[o * N4CH + loc];
            ax += a.x * a.x; ay += a.y * a.y; az += a.z * a.z; aw += a.w * a.w;
        }
    }
    // float4 index i4 = o*6936 + t + 256j; dim-group g = (i4 mod 16) = (t + 8o) & 15
    __shared__ float4 red[256];
    red[t] = make_float4(ax, ay, az, aw);
    __syncthreads();
    if (t < 16) {
        int t0 = (t - 8 * o) & 15;   // threads whose group == t
        float sx = 0.f, sy = 0.f, sz = 0.f, sw = 0.f;
        #pragma unroll
        for (int j = 0; j < 16; ++j) {
            float4 a = red[t0 + 16 * j];
            sx += a.x; sy += a.y; sz += a.z; sw += a.w;
        }
        float* dst = partial + ((size_t)(b * OCT + o)) * D_ + 4 * t;
        dst[0] = sx; dst[1] = sy; dst[2] = sz; dst[3] = sw;
    }
}

// ---------------- pass 1b: combine partials -> inv_norm
// block 64: code half-norms, hn-ascending sort, permuted code table
__global__ __launch_bounds__(256) void norms_combine_kernel(const float* __restrict__ partial,
                                                            const float* __restrict__ codes,
                                                            float* __restrict__ inv_norm,
                                                            float* __restrict__ hns,
                                                            unsigned char* __restrict__ ksrt,
                                                            float* __restrict__ scodes) {
    int t = threadIdx.x;
    if (blockIdx.x == B_) {
        __shared__ float shn[KC];
        float myhn = 0.f;
        if (t < KC) {
            float s = 0.f;
            #pragma unroll 8
            for (int d = 0; d < D_; ++d) { float c = codes[t * D_ + d]; s += c * c; }
            myhn = 0.5f * s;
            shn[t] = myhn;
        }
        __syncthreads();
        if (t < KC) {
            int rank = 0;
            for (int j = 0; j < KC; ++j) {
                float h = shn[j];
                rank += (h < myhn) || (h == myhn && j < t);
            }
            hns[rank] = myhn;
            ksrt[rank] = (unsigned char)t;
            const float4* src = (const float4*)(codes + t * D_);
            float4* dst = (float4*)(scodes + rank * D_);
            #pragma unroll
            for (int j = 0; j < 16; ++j) dst[j] = src[j];
        }
        return;
    }
    int b = blockIdx.x;
    if (t < D_) {
        float s = 0.f;
        #pragma unroll
        for (int o = 0; o < OCT; ++o) s += partial[((size_t)(b * OCT + o)) * D_ + t];
        inv_norm[b * D_ + t] = 1.f / fmaxf(sqrtf(s), 1e-12f);
    }
}

// ---------------- pass 2: assignment with hn-sorted Cauchy-Schwarz pruning
__global__ __launch_bounds__(256) void assign_kernel(const float* __restrict__ feat,
                                                     const float* __restrict__ scodes,
                                                     const float* __restrict__ inv_norm,
                                                     const float* __restrict__ hns,
                                                     const unsigned char* __restrict__ ksrt,
                                                     unsigned char* __restrict__ kout,
                                                     float* __restrict__ rinvout,
                                                     unsigned short* __restrict__ rankout,
                                                     int* __restrict__ counts) {
    __shared__ float4 lc[SLIM * 16];     // 16384 B: first 64 sorted code rows
    __shared__ float  lhns[KC];
    __shared__ unsigned char lks[KC];
    int t = threadIdx.x;
    const float4* sc4 = (const float4*)scodes;
    for (int i = t; i < SLIM * 16; i += 256) lc[i] = sc4[i];
    for (int i = t; i < KC; i += 256) { lhns[i] = hns[i]; lks[i] = ksrt[i]; }
    __syncthreads();

    int p = blockIdx.x * 256 + t;        // grid exact: 867*256 == NPTS
    int b = p / NPB;

    float v[D_];
    float q = 0.f;
    {
        const float4* f0 = (const float4*)(feat + (size_t)p * D_);
        const float4* n0 = (const float4*)(inv_norm + b * D_);
        #pragma unroll
        for (int j = 0; j < 16; ++j) {
            float4 a = f0[j], w = n0[j];
            v[4*j+0] = a.x * w.x; v[4*j+1] = a.y * w.y;
            v[4*j+2] = a.z * w.z; v[4*j+3] = a.w * w.w;
            q += v[4*j+0]*v[4*j+0] + v[4*j+1]*v[4*j+1]
               + v[4*j+2]*v[4*j+2] + v[4*j+3]*v[4*j+3];
        }
    }
    float bw = sqrtf(q);                 // ||vw||

    float best = -3.0e38f;
    int kb = 0;
    int i = 0;
    for (; i < SLIM; ++i) {
        float hn = lhns[i];
        float bnd = fmaf(bw, sqrtf(hn + hn), -hn);   // Cauchy-Schwarz upper bound
        if (__all(bnd + 1e-3f < best)) break;        // monotone in i -> safe break
        float a0 = 0.f, a1 = 0.f, a2 = 0.f, a3 = 0.f;
        #pragma unroll
        for (int j = 0; j < 16; ++j) {
            float4 c = lc[i * 16 + j];
            a0 = fmaf(v[4*j+0], c.x, a0); a1 = fmaf(v[4*j+1], c.y, a1);
            a2 = fmaf(v[4*j+2], c.z, a2); a3 = fmaf(v[4*j+3], c.w, a3);
        }
        float s = (a0 + a1) + (a2 + a3) - hn;
        if (s > best) { best = s; kb = i; }
    }
    if (i == SLIM) {                     // rare tail: fall back to global reads
        for (; i < KC; ++i) {
            float hn = lhns[i];
            float bnd = fmaf(bw, sqrtf(hn + hn), -hn);
            if (__all(bnd + 1e-3f < best)) break;
            float a0 = 0.f, a1 = 0.f, a2 = 0.f, a3 = 0.f;
            #pragma unroll
            for (int j = 0; j < 16; ++j) {
                float4 c = sc4[i * 16 + j];
                a0 = fmaf(v[4*j+0], c.x, a0); a1 = fmaf(v[4*j+1], c.y, a1);
                a2 = fmaf(v[4*j+2], c.z, a2); a3 = fmaf(v[4*j+3], c.w, a3);
            }
            float s = (a0 + a1) + (a2 + a3) - hn;
            if (s > best) { best = s; kb = i; }
        }
    }

    int k0 = (int)lks[kb];
    float rinv = 1.f / (sqrtf(fmaxf(q - 2.f * best, 0.f)) + 1e-8f);
    kout[p] = (unsigned char)k0;
    rinvout[p] = rinv;
    int r = atomicAdd(&counts[b * KC + k0], 1);
    rankout[p] = (unsigned short)r;
}

// ---------------- pass 3: per-batch exclusive prefix over 248 bin counts
__global__ __launch_bounds__(256) void prefix_kernel(const int* __restrict__ counts,
                                                     int* __restrict__ base) {
    __shared__ int lcnt[KC];
    __shared__ int lbase[KC];
    int b = blockIdx.x, t = threadIdx.x;
    if (t < KC) lcnt[t] = counts[b * KC + t];
    __syncthreads();
    if (t == 0) {
        int run = 0;
        for (int k = 0; k < KC; ++k) { lbase[k] = run; run += lcnt[k]; }
    }
    __syncthreads();
    if (t < KC) base[b * KC + t] = lbase[t];
}

// ---------------- pass 4: scatter points into sorted bin order
__global__ __launch_bounds__(256) void scatter_kernel(const unsigned char* __restrict__ kout,
                                                      const float* __restrict__ rinvout,
                                                      const unsigned short* __restrict__ rankout,
                                                      const int* __restrict__ base,
                                                      unsigned short* __restrict__ spidx,
                                                      float* __restrict__ srinv,
                                                      unsigned char* __restrict__ skbuf) {
    int p = blockIdx.x * 256 + threadIdx.x;
    if (p >= NPTS) return;
    int b = p / NPB;
    int k = (int)kout[p];
    int pos = b * NPB + base[b * KC + k] + (int)rankout[p];
    spidx[pos] = (unsigned short)(p - b * NPB);
    srinv[pos] = rinvout[p];
    skbuf[pos] = (unsigned char)k;
}

// ---------------- pass 5: load-balanced segmented aggregation (skew-proof)
__global__ __launch_bounds__(256) void aggregate_kernel(const float* __restrict__ feat,
                                                        const unsigned short* __restrict__ spidx,
                                                        const unsigned char* __restrict__ skbuf,
                                                        const float* __restrict__ srinv,
                                                        float* __restrict__ vacc,
                                                        float* __restrict__ Sacc) {
    int wv = threadIdx.x >> 6, lane = threadIdx.x & 63;
    int chunk = blockIdx.x * 4 + wv;
    if (chunk >= B_ * CHPB) return;
    int b = chunk / CHPB, j = chunk % CHPB;
    int c0 = j * 64;
    int len = NPB - c0; if (len > 64) len = 64;
    int sbase = b * NPB;
    int pos = sbase + c0 + ((lane < len) ? lane : 0);
    int myp = (int)spidx[pos];
    int myk = (int)skbuf[pos];
    float myr = srinv[pos];
    const float* fb = feat + (size_t)sbase * D_ + lane;

    float acc = 0.f, Sr = 0.f;
    int kcur = -1;
    for (int i = 0; i < len; i += 4) {
        int n = len - i; if (n > 4) n = 4;
        float x[4], rr[4];
        int kk[4];
        #pragma unroll
        for (int u = 0; u < 4; ++u) {
            if (u < n) {
                int p = __shfl(myp, i + u);
                kk[u] = __shfl(myk, i + u);
                rr[u] = __shfl(myr, i + u);
                x[u] = fb[(size_t)p * D_];
            }
        }
        for (int u = 0; u < n; ++u) {
            if (kk[u] != kcur) {
                if (kcur >= 0) {
                    atomicAdd(vacc + ((size_t)b * KC + kcur) * D_ + lane, acc);
                    if (lane == 0) atomicAdd(Sacc + b * KC + kcur, Sr);
                }
                kcur = kk[u]; acc = 0.f; Sr = 0.f;
            }
            acc = fmaf(x[u], rr[u], acc);
            Sr += rr[u];
        }
    }
    if (kcur >= 0) {
        atomicAdd(vacc + ((size_t)b * KC + kcur) * D_ + lane, acc);
        if (lane == 0) atomicAdd(Sacc + b * KC + kcur, Sr);
    }
}

// ---------------- pass 6: finalize vlad + per-batch standardize (fused)
__global__ __launch_bounds__(1024) void final_std_kernel(const float* __restrict__ vacc,
                                                         const float* __restrict__ Sacc,
                                                         const float* __restrict__ codes,
                                                         const float* __restrict__ inv_norm,
                                                         float* __restrict__ out) {
    __shared__ float val[KC * APAD];   // 64480 B
    __shared__ float Sl[KC];
    __shared__ float invl[D_];
    __shared__ double rs[1024], rss[1024];
    int b = blockIdx.x, t = threadIdx.x;
    if (t < KC) Sl[t] = Sacc[b * KC + t];
    if (t < D_) invl[t] = inv_norm[b * D_ + t];
    __syncthreads();

    const float* va = vacc + (size_t)b * NV;
    double s = 0.0, ss = 0.0;
    for (int i = t; i < NV; i += 1024) {
        int k = i >> 6, d = i & 63;
        float v = invl[d] * va[i] - codes[i] * Sl[k];
        val[k * APAD + d] = v;
        s += (double)v;
        ss += (double)v * (double)v;
    }
    rs[t] = s; rss[t] = ss;
    __syncthreads();
    for (int off = 512; off > 0; off >>= 1) {
        if (t < off) { rs[t] += rs[t + off]; rss[t] += rss[t + off]; }
        __syncthreads();
    }
    __shared__ float fmean, fscale;
    if (t == 0) {
        double S = rs[0], SS = rss[0];
        double mean = S / (double)NV;
        double var = (SS - S * S / (double)NV) / (double)(NV - 1);
        double sd = sqrt(var > 0.0 ? var : 0.0);
        fmean = (float)mean;
        fscale = (float)(1.0 / (sd + 1e-8));
    }
    __syncthreads();
    float m = fmean, sc = fscale;
    float* row = out + (size_t)b * NV;
    for (int i = t; i < NV; i += 1024) {
        int k = i >> 6, d = i & 63;
        row[i] = (val[k * APAD + d] - m) * sc;
    }
}

extern "C" void kernel_launch(void* const* d_in, const int* in_sizes, int n_in,
                              void* d_out, int out_size, void* d_ws, size_t ws_size,
                              hipStream_t stream) {
    const float* feat  = (const float*)d_in[0];
    const float* codes = (const float*)d_in[1];
    float* out = (float*)d_out;

    char* ws = (char*)d_ws;
    float* inv_norm       = (float*)(ws);                     // 16384 B -> 16384
    float* hns            = (float*)(ws + 16384);             //   992 B -> 17408 (pad)
    unsigned char* ksrt   = (unsigned char*)(ws + 17408);     //   248 B -> 17920 (pad)
    float* scodes         = (float*)(ws + 17920);             // 63488 B -> 81408
    float* partial        = (float*)(ws + 81408);             // 131072 B -> 212480
    // --- zeroed region (one memset): counts, Sacc, vacc ---
    int*   counts         = (int*)  (ws + 212480);            // 63488 B -> 275968
    float* Sacc           = (float*)(ws + 275968);            // 63488 B -> 339456
    float* vacc           = (float*)(ws + 339456);            // 4063232 B -> 4402688
    // ------------------------------------------------------
    int*   basep          = (int*)  (ws + 4402688);           // 63488 B -> 4466176
    unsigned short* rank  = (unsigned short*)(ws + 4466176);  // 443904 B -> 4910080
    unsigned char* kbuf   = (unsigned char*)(ws + 4910080);   // 221952 B -> 5132032
    float* rinvbuf        = (float*)(ws + 5132032);           // 887808 B -> 6019840
    unsigned short* spidx = (unsigned short*)(ws + 6019840);  // 443904 B -> 6463744
    float* srinv          = (float*)(ws + 6463744);           // 887808 B -> 7351552
    unsigned char* skbuf  = (unsigned char*)(ws + 7351552);   // 221952 B -> 7573504

    hipMemsetAsync(ws + 212480, 0, 4402688 - 212480, stream);
    hipLaunchKernelGGL(norms_part_kernel, dim3(B_ * OCT), dim3(256), 0, stream,
                       feat, partial);
    hipLaunchKernelGGL(norms_combine_kernel, dim3(B_ + 1), dim3(256), 0, stream,
                       partial, codes, inv_norm, hns, ksrt, scodes);
    hipLaunchKernelGGL(assign_kernel, dim3(NPTS / 256), dim3(256), 0, stream,
                       feat, scodes, inv_norm, hns, ksrt, kbuf, rinvbuf, rank, counts);
    hipLaunchKernelGGL(prefix_kernel, dim3(B_), dim3(256), 0, stream, counts, basep);
    hipLaunchKernelGGL(scatter_kernel, dim3((NPTS + 255) / 256), dim3(256), 0, stream,
                       kbuf, rinvbuf, rank, basep, spidx, srinv, skbuf);
    hipLaunchKernelGGL(aggregate_kernel, dim3((B_ * CHPB + 3) / 4), dim3(256), 0, stream,
                       feat, spidx, skbuf, srinv, vacc, Sacc);
    hipLaunchKernelGGL(final_std_kernel, dim3(B_), dim3(1024), 0, stream,
                       vacc, Sacc, codes, inv_norm, out);
}

// Round 6
// 98.269 us; speedup vs baseline: 2.6461x; 2.6461x over previous
//
#include <hip/hip_runtime.h>
#include <math.h>

#define B_   64
#define NPB  3468            // points (visual words) per batch
#define NPTS (B_ * NPB)      // 221952
#define KC   248
#define D_   64
#define NV   (KC * D_)       // 15872 per-batch vlad elements
#define OCT  8               // norms: chunks per batch
#define N4PB (NPB * D_ / 4)  // 55488 float4s per batch
#define N4CH (N4PB / OCT)    // 6936 float4s per chunk
#define CHPB 55              // aggregation chunks per batch (54*64 + 12)
#define APAD 65
#define SLIM 64              // sorted code rows staged in LDS

// ---------------- pass 1a: partial sums of squares per (b, chunk, d)
__global__ __launch_bounds__(256) void norms_part_kernel(const float* __restrict__ feat,
                                                         float* __restrict__ partial) {
    int b = blockIdx.x >> 3, o = blockIdx.x & 7, t = threadIdx.x;
    const float4* f = (const float4*)(feat + (size_t)b * (NPB * D_));
    float ax = 0.f, ay = 0.f, az = 0.f, aw = 0.f;
    for (int j = 0; j < (N4CH + 255) / 256; ++j) {
        int loc = t + j * 256;
        if (loc < N4CH) {
            float4 a = f[o * N4CH + loc];
            ax += a.x * a.x; ay += a.y * a.y; az += a.z * a.z; aw += a.w * a.w;
        }
    }
    // float4 index i4 = o*6936 + t + 256j; dim-group g = (i4 mod 16) = (t + 8o) & 15
    __shared__ float4 red[256];
    red[t] = make_float4(ax, ay, az, aw);
    __syncthreads();
    if (t < 16) {
        int t0 = (t - 8 * o) & 15;   // threads whose group == t
        float sx = 0.f, sy = 0.f, sz = 0.f, sw = 0.f;
        #pragma unroll
        for (int j = 0; j < 16; ++j) {
            float4 a = red[t0 + 16 * j];
            sx += a.x; sy += a.y; sz += a.z; sw += a.w;
        }
        float* dst = partial + ((size_t)(b * OCT + o)) * D_ + 4 * t;
        dst[0] = sx; dst[1] = sy; dst[2] = sz; dst[3] = sw;
    }
}

// ---------------- pass 1b: combine partials -> inv_norm
// block 64: code half-norms, hn-ascending sort, permuted code table
__global__ __launch_bounds__(256) void norms_combine_kernel(const float* __restrict__ partial,
                                                            const float* __restrict__ codes,
                                                            float* __restrict__ inv_norm,
                                                            float* __restrict__ hns,
                                                            unsigned char* __restrict__ ksrt,
                                                            float* __restrict__ scodes) {
    int t = threadIdx.x;
    if (blockIdx.x == B_) {
        __shared__ float shn[KC];
        float myhn = 0.f;
        if (t < KC) {
            float s = 0.f;
            #pragma unroll 8
            for (int d = 0; d < D_; ++d) { float c = codes[t * D_ + d]; s += c * c; }
            myhn = 0.5f * s;
            shn[t] = myhn;
        }
        __syncthreads();
        if (t < KC) {
            int rank = 0;
            for (int j = 0; j < KC; ++j) {
                float h = shn[j];
                rank += (h < myhn) || (h == myhn && j < t);
            }
            hns[rank] = myhn;
            ksrt[rank] = (unsigned char)t;
            const float4* src = (const float4*)(codes + t * D_);
            float4* dst = (float4*)(scodes + rank * D_);
            #pragma unroll
            for (int j = 0; j < 16; ++j) dst[j] = src[j];
        }
        return;
    }
    int b = blockIdx.x;
    if (t < D_) {
        float s = 0.f;
        #pragma unroll
        for (int o = 0; o < OCT; ++o) s += partial[((size_t)(b * OCT + o)) * D_ + t];
        inv_norm[b * D_ + t] = 1.f / fmaxf(sqrtf(s), 1e-12f);
    }
}

// ---------------- pass 2: assignment with hn-sorted Cauchy-Schwarz pruning.
// Rank assignment via per-block LDS histogram + per-block range reservation:
// global counter contention drops from ~bin_size (~1500) to <=14 per counter.
__global__ __launch_bounds__(256) void assign_kernel(const float* __restrict__ feat,
                                                     const float* __restrict__ scodes,
                                                     const float* __restrict__ inv_norm,
                                                     const float* __restrict__ hns,
                                                     const unsigned char* __restrict__ ksrt,
                                                     unsigned char* __restrict__ kout,
                                                     float* __restrict__ rinvout,
                                                     unsigned short* __restrict__ rankout,
                                                     int* __restrict__ counts) {
    __shared__ float4 lc[SLIM * 16];     // 16384 B: first 64 sorted code rows
    __shared__ float  lhns[KC];
    __shared__ unsigned char lks[KC];
    __shared__ int hist[2 * KC];         // block can straddle one batch boundary
    __shared__ int gbase[2 * KC];
    int t = threadIdx.x;
    const float4* sc4 = (const float4*)scodes;
    for (int i = t; i < SLIM * 16; i += 256) lc[i] = sc4[i];
    for (int i = t; i < KC; i += 256) { lhns[i] = hns[i]; lks[i] = ksrt[i]; }
    for (int i = t; i < 2 * KC; i += 256) hist[i] = 0;
    __syncthreads();

    int p = blockIdx.x * 256 + t;        // grid exact: 867*256 == NPTS
    int b = p / NPB;
    int bfirst = (blockIdx.x * 256) / NPB;
    int lb = b - bfirst;                 // 0 or 1

    float v[D_];
    float q = 0.f;
    {
        const float4* f0 = (const float4*)(feat + (size_t)p * D_);
        const float4* n0 = (const float4*)(inv_norm + b * D_);
        #pragma unroll
        for (int j = 0; j < 16; ++j) {
            float4 a = f0[j], w = n0[j];
            v[4*j+0] = a.x * w.x; v[4*j+1] = a.y * w.y;
            v[4*j+2] = a.z * w.z; v[4*j+3] = a.w * w.w;
            q += v[4*j+0]*v[4*j+0] + v[4*j+1]*v[4*j+1]
               + v[4*j+2]*v[4*j+2] + v[4*j+3]*v[4*j+3];
        }
    }
    float bw = sqrtf(q);                 // ||vw||

    float best = -3.0e38f;
    int kb = 0;
    int i = 0;
    for (; i < SLIM; ++i) {
        float hn = lhns[i];
        float bnd = fmaf(bw, sqrtf(hn + hn), -hn);   // Cauchy-Schwarz upper bound
        if (__all(bnd + 1e-3f < best)) break;        // monotone in i -> safe break
        float a0 = 0.f, a1 = 0.f, a2 = 0.f, a3 = 0.f;
        #pragma unroll
        for (int j = 0; j < 16; ++j) {
            float4 c = lc[i * 16 + j];
            a0 = fmaf(v[4*j+0], c.x, a0); a1 = fmaf(v[4*j+1], c.y, a1);
            a2 = fmaf(v[4*j+2], c.z, a2); a3 = fmaf(v[4*j+3], c.w, a3);
        }
        float s = (a0 + a1) + (a2 + a3) - hn;
        if (s > best) { best = s; kb = i; }
    }
    if (i == SLIM) {                     // rare tail: fall back to global reads
        for (; i < KC; ++i) {
            float hn = lhns[i];
            float bnd = fmaf(bw, sqrtf(hn + hn), -hn);
            if (__all(bnd + 1e-3f < best)) break;
            float a0 = 0.f, a1 = 0.f, a2 = 0.f, a3 = 0.f;
            #pragma unroll
            for (int j = 0; j < 16; ++j) {
                float4 c = sc4[i * 16 + j];
                a0 = fmaf(v[4*j+0], c.x, a0); a1 = fmaf(v[4*j+1], c.y, a1);
                a2 = fmaf(v[4*j+2], c.z, a2); a3 = fmaf(v[4*j+3], c.w, a3);
            }
            float s = (a0 + a1) + (a2 + a3) - hn;
            if (s > best) { best = s; kb = i; }
        }
    }

    int k0 = (int)lks[kb];
    float rinv = 1.f / (sqrtf(fmaxf(q - 2.f * best, 0.f)) + 1e-8f);
    kout[p] = (unsigned char)k0;
    rinvout[p] = rinv;

    int rloc = atomicAdd(&hist[lb * KC + k0], 1);    // LDS, block-local rank
    __syncthreads();
    for (int j2 = t; j2 < 2 * KC; j2 += 256) {       // reserve global ranges
        int h = hist[j2];
        if (h > 0) gbase[j2] = atomicAdd(&counts[bfirst * KC + j2], h);
    }
    __syncthreads();
    rankout[p] = (unsigned short)(gbase[lb * KC + k0] + rloc);
}

// ---------------- pass 3: per-batch exclusive prefix over 248 bin counts
__global__ __launch_bounds__(256) void prefix_kernel(const int* __restrict__ counts,
                                                     int* __restrict__ base) {
    __shared__ int lcnt[KC];
    __shared__ int lbase[KC];
    int b = blockIdx.x, t = threadIdx.x;
    if (t < KC) lcnt[t] = counts[b * KC + t];
    __syncthreads();
    if (t == 0) {
        int run = 0;
        for (int k = 0; k < KC; ++k) { lbase[k] = run; run += lcnt[k]; }
    }
    __syncthreads();
    if (t < KC) base[b * KC + t] = lbase[t];
}

// ---------------- pass 4: scatter points into sorted bin order
__global__ __launch_bounds__(256) void scatter_kernel(const unsigned char* __restrict__ kout,
                                                      const float* __restrict__ rinvout,
                                                      const unsigned short* __restrict__ rankout,
                                                      const int* __restrict__ base,
                                                      unsigned short* __restrict__ spidx,
                                                      float* __restrict__ srinv,
                                                      unsigned char* __restrict__ skbuf) {
    int p = blockIdx.x * 256 + threadIdx.x;
    if (p >= NPTS) return;
    int b = p / NPB;
    int k = (int)kout[p];
    int pos = b * NPB + base[b * KC + k] + (int)rankout[p];
    spidx[pos] = (unsigned short)(p - b * NPB);
    srinv[pos] = rinvout[p];
    skbuf[pos] = (unsigned char)k;
}

// ---------------- pass 5: load-balanced segmented aggregation (skew-proof)
__global__ __launch_bounds__(256) void aggregate_kernel(const float* __restrict__ feat,
                                                        const unsigned short* __restrict__ spidx,
                                                        const unsigned char* __restrict__ skbuf,
                                                        const float* __restrict__ srinv,
                                                        float* __restrict__ vacc,
                                                        float* __restrict__ Sacc) {
    int wv = threadIdx.x >> 6, lane = threadIdx.x & 63;
    int chunk = blockIdx.x * 4 + wv;
    if (chunk >= B_ * CHPB) return;
    int b = chunk / CHPB, j = chunk % CHPB;
    int c0 = j * 64;
    int len = NPB - c0; if (len > 64) len = 64;
    int sbase = b * NPB;
    int pos = sbase + c0 + ((lane < len) ? lane : 0);
    int myp = (int)spidx[pos];
    int myk = (int)skbuf[pos];
    float myr = srinv[pos];
    const float* fb = feat + (size_t)sbase * D_ + lane;

    float acc = 0.f, Sr = 0.f;
    int kcur = -1;
    for (int i = 0; i < len; i += 4) {
        int n = len - i; if (n > 4) n = 4;
        float x[4], rr[4];
        int kk[4];
        #pragma unroll
        for (int u = 0; u < 4; ++u) {
            if (u < n) {
                int p = __shfl(myp, i + u);
                kk[u] = __shfl(myk, i + u);
                rr[u] = __shfl(myr, i + u);
                x[u] = fb[(size_t)p * D_];
            }
        }
        for (int u = 0; u < n; ++u) {
            if (kk[u] != kcur) {
                if (kcur >= 0) {
                    atomicAdd(vacc + ((size_t)b * KC + kcur) * D_ + lane, acc);
                    if (lane == 0) atomicAdd(Sacc + b * KC + kcur, Sr);
                }
                kcur = kk[u]; acc = 0.f; Sr = 0.f;
            }
            acc = fmaf(x[u], rr[u], acc);
            Sr += rr[u];
        }
    }
    if (kcur >= 0) {
        atomicAdd(vacc + ((size_t)b * KC + kcur) * D_ + lane, acc);
        if (lane == 0) atomicAdd(Sacc + b * KC + kcur, Sr);
    }
}

// ---------------- pass 6: finalize vlad + per-batch standardize (fused)
__global__ __launch_bounds__(1024) void final_std_kernel(const float* __restrict__ vacc,
                                                         const float* __restrict__ Sacc,
                                                         const float* __restrict__ codes,
                                                         const float* __restrict__ inv_norm,
                                                         float* __restrict__ out) {
    __shared__ float val[KC * APAD];   // 64480 B
    __shared__ float Sl[KC];
    __shared__ float invl[D_];
    __shared__ double rs[1024], rss[1024];
    int b = blockIdx.x, t = threadIdx.x;
    if (t < KC) Sl[t] = Sacc[b * KC + t];
    if (t < D_) invl[t] = inv_norm[b * D_ + t];
    __syncthreads();

    const float* va = vacc + (size_t)b * NV;
    double s = 0.0, ss = 0.0;
    for (int i = t; i < NV; i += 1024) {
        int k = i >> 6, d = i & 63;
        float v = invl[d] * va[i] - codes[i] * Sl[k];
        val[k * APAD + d] = v;
        s += (double)v;
        ss += (double)v * (double)v;
    }
    rs[t] = s; rss[t] = ss;
    __syncthreads();
    for (int off = 512; off > 0; off >>= 1) {
        if (t < off) { rs[t] += rs[t + off]; rss[t] += rss[t + off]; }
        __syncthreads();
    }
    __shared__ float fmean, fscale;
    if (t == 0) {
        double S = rs[0], SS = rss[0];
        double mean = S / (double)NV;
        double var = (SS - S * S / (double)NV) / (double)(NV - 1);
        double sd = sqrt(var > 0.0 ? var : 0.0);
        fmean = (float)mean;
        fscale = (float)(1.0 / (sd + 1e-8));
    }
    __syncthreads();
    float m = fmean, sc = fscale;
    float* row = out + (size_t)b * NV;
    for (int i = t; i < NV; i += 1024) {
        int k = i >> 6, d = i & 63;
        row[i] = (val[k * APAD + d] - m) * sc;
    }
}

extern "C" void kernel_launch(void* const* d_in, const int* in_sizes, int n_in,
                              void* d_out, int out_size, void* d_ws, size_t ws_size,
                              hipStream_t stream) {
    const float* feat  = (const float*)d_in[0];
    const float* codes = (const float*)d_in[1];
    float* out = (float*)d_out;

    char* ws = (char*)d_ws;
    float* inv_norm       = (float*)(ws);                     // 16384 B -> 16384
    float* hns            = (float*)(ws + 16384);             //   992 B -> 17408 (pad)
    unsigned char* ksrt   = (unsigned char*)(ws + 17408);     //   248 B -> 17920 (pad)
    float* scodes         = (float*)(ws + 17920);             // 63488 B -> 81408
    float* partial        = (float*)(ws + 81408);             // 131072 B -> 212480
    // --- zeroed region (one memset): counts, Sacc, vacc ---
    int*   counts         = (int*)  (ws + 212480);            // 63488 B -> 275968
    float* Sacc           = (float*)(ws + 275968);            // 63488 B -> 339456
    float* vacc           = (float*)(ws + 339456);            // 4063232 B -> 4402688
    // ------------------------------------------------------
    int*   basep          = (int*)  (ws + 4402688);           // 63488 B -> 4466176
    unsigned short* rank  = (unsigned short*)(ws + 4466176);  // 443904 B -> 4910080
    unsigned char* kbuf   = (unsigned char*)(ws + 4910080);   // 221952 B -> 5132032
    float* rinvbuf        = (float*)(ws + 5132032);           // 887808 B -> 6019840
    unsigned short* spidx = (unsigned short*)(ws + 6019840);  // 443904 B -> 6463744
    float* srinv          = (float*)(ws + 6463744);           // 887808 B -> 7351552
    unsigned char* skbuf  = (unsigned char*)(ws + 7351552);   // 221952 B -> 7573504

    hipMemsetAsync(ws + 212480, 0, 4402688 - 212480, stream);
    hipLaunchKernelGGL(norms_part_kernel, dim3(B_ * OCT), dim3(256), 0, stream,
                       feat, partial);
    hipLaunchKernelGGL(norms_combine_kernel, dim3(B_ + 1), dim3(256), 0, stream,
                       partial, codes, inv_norm, hns, ksrt, scodes);
    hipLaunchKernelGGL(assign_kernel, dim3(NPTS / 256), dim3(256), 0, stream,
                       feat, scodes, inv_norm, hns, ksrt, kbuf, rinvbuf, rank, counts);
    hipLaunchKernelGGL(prefix_kernel, dim3(B_), dim3(256), 0, stream, counts, basep);
    hipLaunchKernelGGL(scatter_kernel, dim3((NPTS + 255) / 256), dim3(256), 0, stream,
                       kbuf, rinvbuf, rank, basep, spidx, srinv, skbuf);
    hipLaunchKernelGGL(aggregate_kernel, dim3((B_ * CHPB + 3) / 4), dim3(256), 0, stream,
                       feat, spidx, skbuf, srinv, vacc, Sacc);
    hipLaunchKernelGGL(final_std_kernel, dim3(B_), dim3(1024), 0, stream,
                       vacc, Sacc, codes, inv_norm, out);
}

// Round 7
// 92.593 us; speedup vs baseline: 2.8083x; 1.0613x over previous
//
#include <hip/hip_runtime.h>
#include <math.h>

#define B_   64
#define NPB  3468            // points (visual words) per batch
#define NPTS (B_ * NPB)      // 221952
#define KC   248
#define D_   64
#define NV   (KC * D_)       // 15872 per-batch vlad elements
#define OCT  8               // norms: chunks per batch
#define N4PB (NPB * D_ / 4)  // 55488 float4s per batch
#define N4CH (N4PB / OCT)    // 6936 float4s per chunk
#define CHPB 55              // aggregation chunks per batch (54*64 + 12)
#define APAD 65
#define SLIM 64              // sorted code rows staged in LDS
#define ZBLK 128             // extra blocks in norms_part that zero the acc region
#define ZN4  261888          // float4s in zero region (4,190,208 B / 16)

// ---------------- pass 1a: partial sums of squares per (b, chunk, d)
// blocks [B_*OCT, B_*OCT+ZBLK): zero the counts/Sacc/vacc region (replaces memset)
__global__ __launch_bounds__(256) void norms_part_kernel(const float* __restrict__ feat,
                                                         float* __restrict__ partial,
                                                         float4* __restrict__ zbase) {
    if (blockIdx.x >= B_ * OCT) {
        int z = blockIdx.x - B_ * OCT;
        const float4 zf = make_float4(0.f, 0.f, 0.f, 0.f);
        for (int i = z * 256 + threadIdx.x; i < ZN4; i += ZBLK * 256) zbase[i] = zf;
        return;
    }
    int b = blockIdx.x >> 3, o = blockIdx.x & 7, t = threadIdx.x;
    const float4* f = (const float4*)(feat + (size_t)b * (NPB * D_));
    float ax = 0.f, ay = 0.f, az = 0.f, aw = 0.f;
    for (int j = 0; j < (N4CH + 255) / 256; ++j) {
        int loc = t + j * 256;
        if (loc < N4CH) {
            float4 a = f[o * N4CH + loc];
            ax += a.x * a.x; ay += a.y * a.y; az += a.z * a.z; aw += a.w * a.w;
        }
    }
    // float4 index i4 = o*6936 + t + 256j; dim-group g = (i4 mod 16) = (t + 8o) & 15
    __shared__ float4 red[256];
    red[t] = make_float4(ax, ay, az, aw);
    __syncthreads();
    if (t < 16) {
        int t0 = (t - 8 * o) & 15;   // threads whose group == t
        float sx = 0.f, sy = 0.f, sz = 0.f, sw = 0.f;
        #pragma unroll
        for (int j = 0; j < 16; ++j) {
            float4 a = red[t0 + 16 * j];
            sx += a.x; sy += a.y; sz += a.z; sw += a.w;
        }
        float* dst = partial + ((size_t)(b * OCT + o)) * D_ + 4 * t;
        dst[0] = sx; dst[1] = sy; dst[2] = sz; dst[3] = sw;
    }
}

// ---------------- pass 1b: combine partials -> inv_norm
// block 64: code half-norms, hn-ascending sort, permuted code table
__global__ __launch_bounds__(256) void norms_combine_kernel(const float* __restrict__ partial,
                                                            const float* __restrict__ codes,
                                                            float* __restrict__ inv_norm,
                                                            float* __restrict__ hns,
                                                            unsigned char* __restrict__ ksrt,
                                                            float* __restrict__ scodes) {
    int t = threadIdx.x;
    if (blockIdx.x == B_) {
        __shared__ float shn[KC];
        float myhn = 0.f;
        if (t < KC) {
            float s = 0.f;
            #pragma unroll 8
            for (int d = 0; d < D_; ++d) { float c = codes[t * D_ + d]; s += c * c; }
            myhn = 0.5f * s;
            shn[t] = myhn;
        }
        __syncthreads();
        if (t < KC) {
            int rank = 0;
            for (int j = 0; j < KC; ++j) {
                float h = shn[j];
                rank += (h < myhn) || (h == myhn && j < t);
            }
            hns[rank] = myhn;
            ksrt[rank] = (unsigned char)t;
            const float4* src = (const float4*)(codes + t * D_);
            float4* dst = (float4*)(scodes + rank * D_);
            #pragma unroll
            for (int j = 0; j < 16; ++j) dst[j] = src[j];
        }
        return;
    }
    int b = blockIdx.x;
    if (t < D_) {
        float s = 0.f;
        #pragma unroll
        for (int o = 0; o < OCT; ++o) s += partial[((size_t)(b * OCT + o)) * D_ + t];
        inv_norm[b * D_ + t] = 1.f / fmaxf(sqrtf(s), 1e-12f);
    }
}

// ---------------- pass 2: assignment with hn-sorted Cauchy-Schwarz pruning.
// Rank assignment via per-block LDS histogram + per-block range reservation:
// global counter contention drops from ~bin_size (~1500) to <=14 per counter.
__global__ __launch_bounds__(256) void assign_kernel(const float* __restrict__ feat,
                                                     const float* __restrict__ scodes,
                                                     const float* __restrict__ inv_norm,
                                                     const float* __restrict__ hns,
                                                     const unsigned char* __restrict__ ksrt,
                                                     unsigned char* __restrict__ kout,
                                                     float* __restrict__ rinvout,
                                                     unsigned short* __restrict__ rankout,
                                                     int* __restrict__ counts) {
    __shared__ float4 lc[SLIM * 16];     // 16384 B: first 64 sorted code rows
    __shared__ float  lhns[KC];
    __shared__ unsigned char lks[KC];
    __shared__ int hist[2 * KC];         // block can straddle one batch boundary
    __shared__ int gbase[2 * KC];
    int t = threadIdx.x;
    const float4* sc4 = (const float4*)scodes;
    for (int i = t; i < SLIM * 16; i += 256) lc[i] = sc4[i];
    for (int i = t; i < KC; i += 256) { lhns[i] = hns[i]; lks[i] = ksrt[i]; }
    for (int i = t; i < 2 * KC; i += 256) hist[i] = 0;
    __syncthreads();

    int p = blockIdx.x * 256 + t;        // grid exact: 867*256 == NPTS
    int b = p / NPB;
    int bfirst = (blockIdx.x * 256) / NPB;
    int lb = b - bfirst;                 // 0 or 1

    float v[D_];
    float q = 0.f;
    {
        const float4* f0 = (const float4*)(feat + (size_t)p * D_);
        const float4* n0 = (const float4*)(inv_norm + b * D_);
        #pragma unroll
        for (int j = 0; j < 16; ++j) {
            float4 a = f0[j], w = n0[j];
            v[4*j+0] = a.x * w.x; v[4*j+1] = a.y * w.y;
            v[4*j+2] = a.z * w.z; v[4*j+3] = a.w * w.w;
            q += v[4*j+0]*v[4*j+0] + v[4*j+1]*v[4*j+1]
               + v[4*j+2]*v[4*j+2] + v[4*j+3]*v[4*j+3];
        }
    }
    float bw = sqrtf(q);                 // ||vw||

    float best = -3.0e38f;
    int kb = 0;
    int i = 0;
    for (; i < SLIM; ++i) {
        float hn = lhns[i];
        float bnd = fmaf(bw, sqrtf(hn + hn), -hn);   // Cauchy-Schwarz upper bound
        if (__all(bnd + 1e-3f < best)) break;        // monotone in i -> safe break
        float a0 = 0.f, a1 = 0.f, a2 = 0.f, a3 = 0.f;
        #pragma unroll
        for (int j = 0; j < 16; ++j) {
            float4 c = lc[i * 16 + j];
            a0 = fmaf(v[4*j+0], c.x, a0); a1 = fmaf(v[4*j+1], c.y, a1);
            a2 = fmaf(v[4*j+2], c.z, a2); a3 = fmaf(v[4*j+3], c.w, a3);
        }
        float s = (a0 + a1) + (a2 + a3) - hn;
        if (s > best) { best = s; kb = i; }
    }
    if (i == SLIM) {                     // rare tail: fall back to global reads
        for (; i < KC; ++i) {
            float hn = lhns[i];
            float bnd = fmaf(bw, sqrtf(hn + hn), -hn);
            if (__all(bnd + 1e-3f < best)) break;
            float a0 = 0.f, a1 = 0.f, a2 = 0.f, a3 = 0.f;
            #pragma unroll
            for (int j = 0; j < 16; ++j) {
                float4 c = sc4[i * 16 + j];
                a0 = fmaf(v[4*j+0], c.x, a0); a1 = fmaf(v[4*j+1], c.y, a1);
                a2 = fmaf(v[4*j+2], c.z, a2); a3 = fmaf(v[4*j+3], c.w, a3);
            }
            float s = (a0 + a1) + (a2 + a3) - hn;
            if (s > best) { best = s; kb = i; }
        }
    }

    int k0 = (int)lks[kb];
    float rinv = 1.f / (sqrtf(fmaxf(q - 2.f * best, 0.f)) + 1e-8f);
    kout[p] = (unsigned char)k0;
    rinvout[p] = rinv;

    int rloc = atomicAdd(&hist[lb * KC + k0], 1);    // LDS, block-local rank
    __syncthreads();
    for (int j2 = t; j2 < 2 * KC; j2 += 256) {       // reserve global ranges
        int h = hist[j2];
        if (h > 0) gbase[j2] = atomicAdd(&counts[bfirst * KC + j2], h);
    }
    __syncthreads();
    rankout[p] = (unsigned short)(gbase[lb * KC + k0] + rloc);
}

// ---------------- pass 3: per-batch exclusive prefix over 248 bin counts
__global__ __launch_bounds__(256) void prefix_kernel(const int* __restrict__ counts,
                                                     int* __restrict__ base) {
    __shared__ int lcnt[KC];
    __shared__ int lbase[KC];
    int b = blockIdx.x, t = threadIdx.x;
    if (t < KC) lcnt[t] = counts[b * KC + t];
    __syncthreads();
    if (t == 0) {
        int run = 0;
        for (int k = 0; k < KC; ++k) { lbase[k] = run; run += lcnt[k]; }
    }
    __syncthreads();
    if (t < KC) base[b * KC + t] = lbase[t];
}

// ---------------- pass 4: scatter points into sorted bin order
__global__ __launch_bounds__(256) void scatter_kernel(const unsigned char* __restrict__ kout,
                                                      const float* __restrict__ rinvout,
                                                      const unsigned short* __restrict__ rankout,
                                                      const int* __restrict__ base,
                                                      unsigned short* __restrict__ spidx,
                                                      float* __restrict__ srinv,
                                                      unsigned char* __restrict__ skbuf) {
    int p = blockIdx.x * 256 + threadIdx.x;
    if (p >= NPTS) return;
    int b = p / NPB;
    int k = (int)kout[p];
    int pos = b * NPB + base[b * KC + k] + (int)rankout[p];
    spidx[pos] = (unsigned short)(p - b * NPB);
    srinv[pos] = rinvout[p];
    skbuf[pos] = (unsigned char)k;
}

// ---------------- pass 5: load-balanced segmented aggregation (skew-proof)
__global__ __launch_bounds__(256) void aggregate_kernel(const float* __restrict__ feat,
                                                        const unsigned short* __restrict__ spidx,
                                                        const unsigned char* __restrict__ skbuf,
                                                        const float* __restrict__ srinv,
                                                        float* __restrict__ vacc,
                                                        float* __restrict__ Sacc) {
    int wv = threadIdx.x >> 6, lane = threadIdx.x & 63;
    int chunk = blockIdx.x * 4 + wv;
    if (chunk >= B_ * CHPB) return;
    int b = chunk / CHPB, j = chunk % CHPB;
    int c0 = j * 64;
    int len = NPB - c0; if (len > 64) len = 64;
    int sbase = b * NPB;
    int pos = sbase + c0 + ((lane < len) ? lane : 0);
    int myp = (int)spidx[pos];
    int myk = (int)skbuf[pos];
    float myr = srinv[pos];
    const float* fb = feat + (size_t)sbase * D_ + lane;

    float acc = 0.f, Sr = 0.f;
    int kcur = -1;
    for (int i = 0; i < len; i += 4) {
        int n = len - i; if (n > 4) n = 4;
        float x[4], rr[4];
        int kk[4];
        #pragma unroll
        for (int u = 0; u < 4; ++u) {
            if (u < n) {
                int p = __shfl(myp, i + u);
                kk[u] = __shfl(myk, i + u);
                rr[u] = __shfl(myr, i + u);
                x[u] = fb[(size_t)p * D_];
            }
        }
        for (int u = 0; u < n; ++u) {
            if (kk[u] != kcur) {
                if (kcur >= 0) {
                    atomicAdd(vacc + ((size_t)b * KC + kcur) * D_ + lane, acc);
                    if (lane == 0) atomicAdd(Sacc + b * KC + kcur, Sr);
                }
                kcur = kk[u]; acc = 0.f; Sr = 0.f;
            }
            acc = fmaf(x[u], rr[u], acc);
            Sr += rr[u];
        }
    }
    if (kcur >= 0) {
        atomicAdd(vacc + ((size_t)b * KC + kcur) * D_ + lane, acc);
        if (lane == 0) atomicAdd(Sacc + b * KC + kcur, Sr);
    }
}

// ---------------- pass 6: finalize vlad + per-batch standardize (fused)
__global__ __launch_bounds__(1024) void final_std_kernel(const float* __restrict__ vacc,
                                                         const float* __restrict__ Sacc,
                                                         const float* __restrict__ codes,
                                                         const float* __restrict__ inv_norm,
                                                         float* __restrict__ out) {
    __shared__ float val[KC * APAD];   // 64480 B
    __shared__ float Sl[KC];
    __shared__ float invl[D_];
    __shared__ double rs[1024], rss[1024];
    int b = blockIdx.x, t = threadIdx.x;
    if (t < KC) Sl[t] = Sacc[b * KC + t];
    if (t < D_) invl[t] = inv_norm[b * D_ + t];
    __syncthreads();

    const float* va = vacc + (size_t)b * NV;
    double s = 0.0, ss = 0.0;
    for (int i = t; i < NV; i += 1024) {
        int k = i >> 6, d = i & 63;
        float v = invl[d] * va[i] - codes[i] * Sl[k];
        val[k * APAD + d] = v;
        s += (double)v;
        ss += (double)v * (double)v;
    }
    rs[t] = s; rss[t] = ss;
    __syncthreads();
    for (int off = 512; off > 0; off >>= 1) {
        if (t < off) { rs[t] += rs[t + off]; rss[t] += rss[t + off]; }
        __syncthreads();
    }
    __shared__ float fmean, fscale;
    if (t == 0) {
        double S = rs[0], SS = rss[0];
        double mean = S / (double)NV;
        double var = (SS - S * S / (double)NV) / (double)(NV - 1);
        double sd = sqrt(var > 0.0 ? var : 0.0);
        fmean = (float)mean;
        fscale = (float)(1.0 / (sd + 1e-8));
    }
    __syncthreads();
    float m = fmean, sc = fscale;
    float* row = out + (size_t)b * NV;
    for (int i = t; i < NV; i += 1024) {
        int k = i >> 6, d = i & 63;
        row[i] = (val[k * APAD + d] - m) * sc;
    }
}

extern "C" void kernel_launch(void* const* d_in, const int* in_sizes, int n_in,
                              void* d_out, int out_size, void* d_ws, size_t ws_size,
                              hipStream_t stream) {
    const float* feat  = (const float*)d_in[0];
    const float* codes = (const float*)d_in[1];
    float* out = (float*)d_out;

    char* ws = (char*)d_ws;
    float* inv_norm       = (float*)(ws);                     // 16384 B -> 16384
    float* hns            = (float*)(ws + 16384);             //   992 B -> 17408 (pad)
    unsigned char* ksrt   = (unsigned char*)(ws + 17408);     //   248 B -> 17920 (pad)
    float* scodes         = (float*)(ws + 17920);             // 63488 B -> 81408
    float* partial        = (float*)(ws + 81408);             // 131072 B -> 212480
    // --- zeroed region (by norms_part extra blocks): counts, Sacc, vacc ---
    int*   counts         = (int*)  (ws + 212480);            // 63488 B -> 275968
    float* Sacc           = (float*)(ws + 275968);            // 63488 B -> 339456
    float* vacc           = (float*)(ws + 339456);            // 4063232 B -> 4402688
    // ----------------------------------------------------------------------
    int*   basep          = (int*)  (ws + 4402688);           // 63488 B -> 4466176
    unsigned short* rank  = (unsigned short*)(ws + 4466176);  // 443904 B -> 4910080
    unsigned char* kbuf   = (unsigned char*)(ws + 4910080);   // 221952 B -> 5132032
    float* rinvbuf        = (float*)(ws + 5132032);           // 887808 B -> 6019840
    unsigned short* spidx = (unsigned short*)(ws + 6019840);  // 443904 B -> 6463744
    float* srinv          = (float*)(ws + 6463744);           // 887808 B -> 7351552
    unsigned char* skbuf  = (unsigned char*)(ws + 7351552);   // 221952 B -> 7573504

    hipLaunchKernelGGL(norms_part_kernel, dim3(B_ * OCT + ZBLK), dim3(256), 0, stream,
                       feat, partial, (float4*)(ws + 212480));
    hipLaunchKernelGGL(norms_combine_kernel, dim3(B_ + 1), dim3(256), 0, stream,
                       partial, codes, inv_norm, hns, ksrt, scodes);
    hipLaunchKernelGGL(assign_kernel, dim3(NPTS / 256), dim3(256), 0, stream,
                       feat, scodes, inv_norm, hns, ksrt, kbuf, rinvbuf, rank, counts);
    hipLaunchKernelGGL(prefix_kernel, dim3(B_), dim3(256), 0, stream, counts, basep);
    hipLaunchKernelGGL(scatter_kernel, dim3((NPTS + 255) / 256), dim3(256), 0, stream,
                       kbuf, rinvbuf, rank, basep, spidx, srinv, skbuf);
    hipLaunchKernelGGL(aggregate_kernel, dim3((B_ * CHPB + 3) / 4), dim3(256), 0, stream,
                       feat, spidx, skbuf, srinv, vacc, Sacc);
    hipLaunchKernelGGL(final_std_kernel, dim3(B_), dim3(1024), 0, stream,
                       vacc, Sacc, codes, inv_norm, out);
}